// Round 9
// baseline (1151.289 us; speedup 1.0000x reference)
//
#include <hip/hip_runtime.h>
#include <hip/hip_bf16.h>

// GCN1: 3-layer GraphConv x 4 graphs -> scalar grand mean.
// R16: phase-batched register GEMM. R15's rotation double-buffer was
// re-serialized by the compiler (VGPR 56, not ~120). R13 proved static
// fully-unrolled register arrays DO get allocated. So: per phase (5 ks),
// load ALL 35 fragments (2A+5B per ks) into static s8v arrays upfront
// (35 independent loads in flight), then 50 MFMAs from registers. No LDS,
// no barriers, launch_bounds(256,2). Grid (4,391,G). Falsifiable marker:
// gemm VGPR_Count >= ~140. Retains R12 8-deep-MLP spmm, R10 graph-
// batching, R9b layouts (64B packed rows, full-line gathers, packed f2
// accumulate, nontemporal stores, padded CSR + degree-sorted perm,
// atomic-free CSR build, layer-3 reduction into double).

#define NN 50000
#define EN 800000
#define PEN 950000        // padded edges per graph (EN + 3*NN upper bound)
#define NCH 64            // CSR chunks per graph
#define CHE 12500         // edges per chunk (NCH*CHE == EN)
#define PBS 50016         // padded per-chunk histogram bytes (>= NN, %4==0)
#define SCB 49            // scan blocks per graph (49*1024 >= NN)
#define DCH 13            // degree-sort chunks per graph
#define DCN 4096          // nodes per degree-sort chunk (13*4096 >= NN)

typedef unsigned int uint;
typedef unsigned short ushort;
typedef unsigned char uchar;
typedef short s8v __attribute__((ext_vector_type(8)));
typedef float f4v __attribute__((ext_vector_type(4)));
typedef float f2v __attribute__((ext_vector_type(2)));
typedef uint u4v __attribute__((ext_vector_type(4)));

__device__ inline ushort f2bf(float f) {
    uint u = __float_as_uint(f);
    uint r = (u + 0x7FFFu + ((u >> 16) & 1u)) >> 16;
    return (ushort)r;
}
__device__ inline uint pk2(float lo, float hi) {
    return (uint)f2bf(lo) | ((uint)f2bf(hi) << 16);
}
__device__ inline f4v mfma16(s8v a, s8v b, f4v c) {
    return __builtin_amdgcn_mfma_f32_16x16x32_bf16(a, b, c, 0, 0, 0);
}
__device__ inline uchar f2fp8(float f) {
    return (uchar)(__builtin_amdgcn_cvt_pk_fp8_f32(f, 0.f, 0, false) & 0xFF);
}
// 16 fp8 bytes -> 8 packed float2 accumulators (v_pk_add_f32).
__device__ inline void acc16(u4v d, f2v* a) {
    a[0] += __builtin_amdgcn_cvt_pk_f32_fp8(d.x, false);
    a[1] += __builtin_amdgcn_cvt_pk_f32_fp8(d.x, true);
    a[2] += __builtin_amdgcn_cvt_pk_f32_fp8(d.y, false);
    a[3] += __builtin_amdgcn_cvt_pk_f32_fp8(d.y, true);
    a[4] += __builtin_amdgcn_cvt_pk_f32_fp8(d.z, false);
    a[5] += __builtin_amdgcn_cvt_pk_f32_fp8(d.z, true);
    a[6] += __builtin_amdgcn_cvt_pk_f32_fp8(d.w, false);
    a[7] += __builtin_amdgcn_cvt_pk_f32_fp8(d.w, true);
}

struct GP { const int* p[4]; };
struct FP { const float* p[4]; };

// ---- CSR build (atomic-free) ----------------------------------------------

__global__ __launch_bounds__(256) void hist_kernel(GP src, GP dst,
                                                   uint* __restrict__ partS,
                                                   uint* __restrict__ partD) {
    int b = blockIdx.x, dir = blockIdx.y, g = blockIdx.z;
    const int* idx = dir ? dst.p[g] : src.p[g];
    __shared__ uint lh[PBS / 4];
    for (int i = threadIdx.x; i < PBS / 4; i += 256) lh[i] = 0;
    __syncthreads();
    int e0 = b * CHE;
    for (int e = e0 + threadIdx.x; e < e0 + CHE; e += 256) {
        uint n = (uint)idx[e];
        atomicAdd(&lh[n >> 2], 1u << (8 * (n & 3)));   // LDS atomic only
    }
    __syncthreads();
    uint* out = (dir ? partD : partS) + (size_t)(g * NCH + b) * (PBS / 4);
    for (int i = threadIdx.x; i < PBS / 4; i += 256) out[i] = lh[i];
}

__global__ __launch_bounds__(256) void reduce_kernel(const uchar* __restrict__ partS,
                                                     uchar* __restrict__ partD,
                                                     float* __restrict__ ns,
                                                     float* __restrict__ nd,
                                                     int* __restrict__ degd) {
    int idx = blockIdx.x * 256 + threadIdx.x;
    if (idx >= 4 * NN) return;
    int g = idx / NN, n = idx - g * NN;
    const uchar* ps = partS + (size_t)(g * NCH) * PBS + n;
    uint ss = 0;
    for (int b = 0; b < NCH; b++) ss += ps[(size_t)b * PBS];
    uchar* pd = partD + (size_t)(g * NCH) * PBS + n;
    uint run = 0;
    for (int b = 0; b < NCH; b++) {
        uint v = pd[(size_t)b * PBS];
        pd[(size_t)b * PBS] = (uchar)run;
        run += v;
    }
    ns[idx] = rsqrtf((float)max(ss, 1u));
    nd[idx] = rsqrtf((float)max(run, 1u));
    degd[idx] = (int)run;
}

// scan over PADDED degree (deg+3)&~3 -> prs row starts (4-edge aligned).
__global__ __launch_bounds__(1024) void scan1_kernel(const int* __restrict__ degd,
                                                     int* __restrict__ rs_all,
                                                     int* __restrict__ bsum) {
    int j = blockIdx.x, g = blockIdx.y;
    int i = j * 1024 + threadIdx.x;
    int v = (i < NN) ? ((degd[g * NN + i] + 3) & ~3) : 0;
    int lane = threadIdx.x & 63, w = threadIdx.x >> 6;
    int x = v;
    #pragma unroll
    for (int off = 1; off < 64; off <<= 1) {
        int t = __shfl_up(x, off, 64);
        if (lane >= off) x += t;
    }
    __shared__ int ws[17];
    if (lane == 63) ws[w] = x;
    __syncthreads();
    if (threadIdx.x == 0) {
        int run = 0;
        #pragma unroll
        for (int k = 0; k < 16; k++) { int t = ws[k]; ws[k] = run; run += t; }
        ws[16] = run;
    }
    __syncthreads();
    if (i < NN) rs_all[g * (NN + 1) + i] = ws[w] + x - v;
    if (threadIdx.x == 0) bsum[g * SCB + j] = ws[16];
}

__global__ void scan2_kernel(int* __restrict__ bsum, int* __restrict__ rs_all) {
    int g = threadIdx.x >> 6, lane = threadIdx.x & 63;
    int v = (lane < SCB) ? bsum[g * SCB + lane] : 0;
    int x = v;
    #pragma unroll
    for (int off = 1; off < 64; off <<= 1) {
        int t = __shfl_up(x, off, 64);
        if (lane >= off) x += t;
    }
    if (lane < SCB) bsum[g * SCB + lane] = x - v;   // exclusive
    if (lane == 63) rs_all[g * (NN + 1) + NN] = x;  // total padded edges
}

__global__ __launch_bounds__(1024) void scan3_kernel(const int* __restrict__ bsum,
                                                     int* __restrict__ rs_all) {
    int j = blockIdx.x, g = blockIdx.y;
    int i = j * 1024 + threadIdx.x;
    int off = bsum[g * SCB + j];
    if (i < NN) rs_all[g * (NN + 1) + i] += off;
}

// fill padded csr with the zero-row id NN (pad slots survive scatter).
__global__ __launch_bounds__(256) void cfill_kernel(uint* __restrict__ csr2) {
    int i = blockIdx.x * 256 + threadIdx.x;
    if (i < 4 * PEN / 2) csr2[i] = (uint)NN | ((uint)NN << 16);
}

__global__ __launch_bounds__(256) void scatter_kernel(GP src, GP dst,
                                                      const int* __restrict__ rs_all,
                                                      const uchar* __restrict__ pf,
                                                      ushort* __restrict__ csr) {
    int b = blockIdx.x, g = blockIdx.y;
    __shared__ uint lc[PBS / 4];
    for (int i = threadIdx.x; i < PBS / 4; i += 256) lc[i] = 0;
    __syncthreads();
    const int* sp = src.p[g];
    const int* dp = dst.p[g];
    const int* rs = rs_all + g * (NN + 1);
    const uchar* pfb = pf + (size_t)(g * NCH + b) * PBS;
    ushort* csrg = csr + (size_t)g * PEN;
    int e0 = b * CHE;
    for (int e = e0 + threadIdx.x; e < e0 + CHE; e += 256) {
        uint d = (uint)dp[e];
        int s = sp[e];
        uint sh = 8 * (d & 3);
        uint old = atomicAdd(&lc[d >> 2], 1u << sh);
        uint r = (old >> sh) & 0xFFu;
        csrg[rs[d] + (int)pfb[d] + (int)r] = (ushort)s;
    }
}

// ---- degree counting sort (chunked, atomic-free) -> perm -------------------

__global__ __launch_bounds__(256) void dhist_kernel(const int* __restrict__ degd,
                                                    int* __restrict__ dhp) {
    int b = blockIdx.x, g = blockIdx.y;
    __shared__ int lh[256];
    lh[threadIdx.x] = 0;
    __syncthreads();
    int n0 = b * DCN, nend = min(n0 + DCN, NN);
    for (int i = n0 + threadIdx.x; i < nend; i += 256) {
        int d = degd[g * NN + i];
        atomicAdd(&lh[d < 255 ? d : 255], 1);   // LDS only
    }
    __syncthreads();
    dhp[(g * DCH + b) * 256 + threadIdx.x] = lh[threadIdx.x];
}

__global__ void dscan_kernel(int* __restrict__ dhp, int* __restrict__ dbase) {
    int tid = threadIdx.x, lane = tid & 63, w = tid >> 6;
    __shared__ int ws[4];
    for (int g = 0; g < 4; g++) {
        int run = 0;
        for (int c = 0; c < DCH; c++) {
            int v = dhp[(g * DCH + c) * 256 + tid];
            dhp[(g * DCH + c) * 256 + tid] = run;
            run += v;
        }
        int x = run;
        #pragma unroll
        for (int off = 1; off < 64; off <<= 1) {
            int t = __shfl_up(x, off, 64);
            if (lane >= off) x += t;
        }
        if (lane == 63) ws[w] = x;
        __syncthreads();
        int prefix = 0;
        for (int j = 0; j < w; j++) prefix += ws[j];
        dbase[g * 256 + tid] = prefix + x - run;
        __syncthreads();
    }
}

__global__ __launch_bounds__(256) void dscatter_kernel(const int* __restrict__ degd,
                                                       const int* __restrict__ dhp,
                                                       const int* __restrict__ dbase,
                                                       int* __restrict__ perm) {
    int b = blockIdx.x, g = blockIdx.y;
    __shared__ int lc[256];
    lc[threadIdx.x] = 0;
    __syncthreads();
    int n0 = b * DCN, nend = min(n0 + DCN, NN);
    for (int i = n0 + threadIdx.x; i < nend; i += 256) {
        int d = degd[g * NN + i];
        d = d < 255 ? d : 255;
        int r = atomicAdd(&lc[d], 1);   // LDS only: within-chunk rank
        int pos = dbase[g * 256 + d] + dhp[(g * DCH + b) * 256 + d] + r;
        perm[g * NN + pos] = i;
    }
}

// ---- zero pad rows (row NN): nxs/nhb consecutive slice blocks --------------

__global__ void padzero_kernel(uint* __restrict__ xs, int nxs,
                               uint* __restrict__ hb, int nhb) {
    int t = threadIdx.x;
    if (t < nxs * 16) xs[(size_t)(t >> 4) * (NN + 1) * 16 + (size_t)NN * 16 + (t & 15)] = 0;
    if (t < nhb * 16) hb[(size_t)(t >> 4) * (NN + 1) * 16 + (size_t)NN * 16 + (t & 15)] = 0;
}

// ---- weight transpose/pad to bf16: Wt[n][k], stride WS = K+8 ---------------

__global__ __launch_bounds__(256) void wtrans_kernel(const float* __restrict__ W,
                                                     ushort* __restrict__ Wt,
                                                     int Kreal, int WS) {
    int idx = blockIdx.x * 256 + threadIdx.x;
    if (idx >= 320 * WS) return;
    int n = idx / WS, k = idx - n * WS;
    float v = (n < 304 && k < Kreal) ? W[k * 304 + n] : 0.f;
    Wt[idx] = f2bf(v);
}

// ---- prescale: xs = fp8(x * ns), [g][2][(NN+1)][64B]; blockIdx.y = graph ---

__global__ __launch_bounds__(256) void prescale_kernel(FP xp,
                                                       const float* __restrict__ ns,
                                                       uint* __restrict__ xs) {
    int g = blockIdx.y;
    const float* x = xp.p[g];
    ns += (size_t)g * NN;
    xs += (size_t)g * 2 * (NN + 1) * 16;
    int idx = blockIdx.x * 256 + threadIdx.x;   // over NN*16 units of 8 floats
    if (idx >= NN * 16) return;
    int row = idx >> 4, j = idx & 15;
    int sl = j >> 3, pos = j & 7;
    float nv = ns[row];
    float4 v0 = ((const float4*)x)[idx * 2];
    float4 v1 = ((const float4*)x)[idx * 2 + 1];
    int p0 = 0, p1 = 0;
    p0 = __builtin_amdgcn_cvt_pk_fp8_f32(v0.x * nv, v0.y * nv, p0, false);
    p0 = __builtin_amdgcn_cvt_pk_fp8_f32(v0.z * nv, v0.w * nv, p0, true);
    p1 = __builtin_amdgcn_cvt_pk_fp8_f32(v1.x * nv, v1.y * nv, p1, false);
    p1 = __builtin_amdgcn_cvt_pk_fp8_f32(v1.z * nv, v1.w * nv, p1, true);
    ((uint2*)xs)[(size_t)sl * (NN + 1) * 8 + row * 8 + pos] = make_uint2((uint)p0, (uint)p1);
}

// ---- SpMM (64B packed rows, 1-line dwordx4 group gathers, 8-deep MLP) ------
// xsl: S slices x [(NN+1)][64B]. Wave = 16 groups x 4 lanes x 16B = 1 line
// per gather. Grid (ceil(NN/64), SL, G). Inner loop: 8 edges/iter, 8 lines
// in flight, two accumulator banks (halved add chains). Rows are 4-edge
// padded; the odd quad is peeled first so the main loop is 8-aligned.
__global__ __launch_bounds__(256) void spmm_kernel(const u4v* __restrict__ xsl,
                                                   const int* __restrict__ prs,
                                                   const ushort* __restrict__ csr,
                                                   const float* __restrict__ nd,
                                                   const int* __restrict__ perm,
                                                   u4v* __restrict__ out,
                                                   int ostride) {
    int g = blockIdx.z, SL = gridDim.y;
    xsl += (size_t)g * SL * (NN + 1) * 4;
    prs += (size_t)g * (NN + 1);
    csr += (size_t)g * PEN;
    nd  += (size_t)g * NN;
    perm += (size_t)g * NN;
    out += (size_t)g * NN * ostride;

    int wv = threadIdx.x >> 6, lane = threadIdx.x & 63;
    int grp = lane >> 2, gl = lane & 3;
    int slot = blockIdx.x * 64 + wv * 16 + grp;
    int sl = blockIdx.y;
    const u4v* base = xsl + (size_t)sl * (NN + 1) * 4 + gl;
    bool ok = slot < NN;
    int node = ok ? perm[slot] : 0;
    int p0 = ok ? prs[node] : 0, p1 = ok ? prs[node + 1] : 0;
    f2v a[8], b[8];
    #pragma unroll
    for (int i = 0; i < 8; i++) { a[i] = (f2v){0.f, 0.f}; b[i] = (f2v){0.f, 0.f}; }
    int e = p0;
    if ((p1 - p0) & 4) {
        uint2 e4 = *(const uint2*)(csr + e);
        uint s0 = e4.x & 0xFFFFu, s1 = e4.x >> 16;
        uint s2 = e4.y & 0xFFFFu, s3 = e4.y >> 16;
        u4v d0 = base[s0 * 4];
        u4v d1 = base[s1 * 4];
        u4v d2 = base[s2 * 4];
        u4v d3 = base[s3 * 4];
        acc16(d0, a); acc16(d1, b); acc16(d2, a); acc16(d3, b);
        e += 4;
    }
    for (; e < p1; e += 8) {
        uint2 q0 = *(const uint2*)(csr + e);
        uint2 q1 = *(const uint2*)(csr + e + 4);
        uint s0 = q0.x & 0xFFFFu, s1 = q0.x >> 16;
        uint s2 = q0.y & 0xFFFFu, s3 = q0.y >> 16;
        uint s4 = q1.x & 0xFFFFu, s5 = q1.x >> 16;
        uint s6 = q1.y & 0xFFFFu, s7 = q1.y >> 16;
        u4v d0 = base[s0 * 4];
        u4v d1 = base[s1 * 4];
        u4v d2 = base[s2 * 4];
        u4v d3 = base[s3 * 4];
        u4v d4 = base[s4 * 4];
        u4v d5 = base[s5 * 4];
        u4v d6 = base[s6 * 4];
        u4v d7 = base[s7 * 4];
        acc16(d0, a); acc16(d1, b); acc16(d2, a); acc16(d3, b);
        acc16(d4, a); acc16(d5, b); acc16(d6, a); acc16(d7, b);
    }
    if (ok) {
        float nv = nd[node];
        f2v nv2 = {nv, nv};
        f2v c0 = (a[0] + b[0]) * nv2, c1 = (a[1] + b[1]) * nv2;
        f2v c2 = (a[2] + b[2]) * nv2, c3 = (a[3] + b[3]) * nv2;
        f2v c4 = (a[4] + b[4]) * nv2, c5 = (a[5] + b[5]) * nv2;
        f2v c6 = (a[6] + b[6]) * nv2, c7 = (a[7] + b[7]) * nv2;
        u4v o0, o1;
        o0.x = pk2(c0[0], c0[1]); o0.y = pk2(c1[0], c1[1]);
        o0.z = pk2(c2[0], c2[1]); o0.w = pk2(c3[0], c3[1]);
        o1.x = pk2(c4[0], c4[1]); o1.y = pk2(c5[0], c5[1]);
        o1.z = pk2(c6[0], c6[1]); o1.w = pk2(c7[0], c7[1]);
        u4v* op = out + (size_t)node * ostride + sl * 8 + gl * 2;
        __builtin_nontemporal_store(o0, op);
        __builtin_nontemporal_store(o1, op + 1);
    }
}

// ---- GEMM (phase-batched register, LDS-free): C = A @ Wt^T, relu(+bias) ----
// Grid (4 n-tiles, row-chunks, G). No LDS/barriers; B direct from L2-hot Wt.
// Per phase (KP ks), ALL 7*KP fragments load into static s8v arrays upfront
// (fully unrolled, static indices -> registers; 35 loads in flight), then
// 10*KP MFMAs run from registers. !REDUCE writes fp8 into 5-slice layout;
// REDUCE sums into double.

template<int KSTEPS, bool REDUCE>
__global__ __launch_bounds__(256, 2) void gemm_kernel(const ushort* __restrict__ A, int astride,
                                                      const ushort* __restrict__ Wt, int ws,
                                                      const float* __restrict__ bias,
                                                      const float* __restrict__ ns,
                                                      uchar* __restrict__ Hout,
                                                      double* __restrict__ accum,
                                                      int M) {
    constexpr int PH = (KSTEPS > 5) ? 2 : 1;
    constexpr int KP = KSTEPS / PH;   // 5 for KSTEPS=10, 4 for KSTEPS=4
    __shared__ float redbuf[4];
    int g = blockIdx.z;
    A += (size_t)g * NN * astride;
    int tid = threadIdx.x, lane = tid & 63, wv = tid >> 6;
    int nb = blockIdx.x * 80;
    int r0 = blockIdx.y * 128 + wv * 32;

    int m15 = lane & 15;
    int kq = (lane >> 4) * 8;
    int ar0 = min(r0 + m15, M - 1);
    int ar1 = min(r0 + 16 + m15, M - 1);
    const ushort* a0p = A + (size_t)ar0 * astride + kq;
    const ushort* a1p = A + (size_t)ar1 * astride + kq;
    const ushort* bp0 = Wt + (size_t)(nb + m15) * ws + kq;

    f4v acc[2][5];
    #pragma unroll
    for (int t = 0; t < 2; t++)
        #pragma unroll
        for (int j = 0; j < 5; j++) acc[t][j] = (f4v){0.f, 0.f, 0.f, 0.f};

    #pragma unroll
    for (int ph = 0; ph < PH; ph++) {
        s8v av[2][KP];
        s8v bv[5][KP];
        #pragma unroll
        for (int k = 0; k < KP; k++) {
            int o = (ph * KP + k) * 32;
            av[0][k] = *(const s8v*)(a0p + o);
            av[1][k] = *(const s8v*)(a1p + o);
            #pragma unroll
            for (int nt = 0; nt < 5; nt++)
                bv[nt][k] = *(const s8v*)(bp0 + (size_t)nt * 16 * ws + o);
        }
        #pragma unroll
        for (int k = 0; k < KP; k++) {
            #pragma unroll
            for (int nt = 0; nt < 5; nt++) {
                acc[0][nt] = mfma16(av[0][k], bv[nt][k], acc[0][nt]);
                acc[1][nt] = mfma16(av[1][k], bv[nt][k], acc[1][nt]);
            }
        }
    }

    int rq = (lane >> 4) * 4;   // C/D: col = lane&15, row = (lane>>4)*4 + reg
    if constexpr (!REDUCE) {
        const float* nsg = ns + (size_t)g * NN;
        uchar* hg = Hout + (size_t)g * 5 * (NN + 1) * 64;
        float nsv[2][4];
        #pragma unroll
        for (int t = 0; t < 2; t++)
            #pragma unroll
            for (int r = 0; r < 4; r++) {
                int row = r0 + t * 16 + rq + r;
                nsv[t][r] = (row < M) ? nsg[row] : 0.f;
            }
        #pragma unroll
        for (int nt = 0; nt < 5; nt++) {
            int col = nb + nt * 16 + m15;
            float bv = (col < 304) ? bias[col] : 0.f;
            int sl = col >> 6, cw = col & 63;
            uchar* hp = hg + (size_t)sl * (NN + 1) * 64 + cw;
            #pragma unroll
            for (int t = 0; t < 2; t++)
                #pragma unroll
                for (int r = 0; r < 4; r++) {
                    int row = r0 + t * 16 + rq + r;
                    if (row < M) {
                        float y = fmaxf(acc[t][nt][r] + bv, 0.f) * nsv[t][r];
                        hp[(size_t)row * 64] = f2fp8(y);
                    }
                }
        }
    } else {
        float s = 0.f;
        #pragma unroll
        for (int nt = 0; nt < 5; nt++) {
            int col = nb + nt * 16 + m15;
            float bv = (col < 304) ? bias[col] : 0.f;
            #pragma unroll
            for (int t = 0; t < 2; t++)
                #pragma unroll
                for (int r = 0; r < 4; r++) {
                    int row = r0 + t * 16 + rq + r;
                    if (row < M && col < 304) s += fmaxf(acc[t][nt][r] + bv, 0.f);
                }
        }
        #pragma unroll
        for (int off = 32; off; off >>= 1) s += __shfl_xor(s, off, 64);
        if (lane == 0) redbuf[wv] = s;
        __syncthreads();
        if (tid == 0) {
            double b = (double)redbuf[0] + redbuf[1] + redbuf[2] + redbuf[3];
            atomicAdd(accum, b);
        }
    }
}

__global__ void finalize_kernel(const double* __restrict__ accum, float* __restrict__ out) {
    out[0] = (float)(accum[0] / (double)(4.0 * NN * 304.0));
}

// ---- host ------------------------------------------------------------------

extern "C" void kernel_launch(void* const* d_in, const int* in_sizes, int n_in,
                              void* d_out, int out_size, void* d_ws, size_t ws_size,
                              hipStream_t stream) {
    char* w = (char*)d_ws;
    auto alloc = [&](size_t bytes) {
        char* p = w;
        w += (bytes + 255) & ~(size_t)255;
        return p;
    };
    double* accum  = (double*)alloc(256);
    int*    degd   = (int*)alloc((size_t)4 * NN * 4);
    int*    rs     = (int*)alloc((size_t)4 * (NN + 1) * 4);   // padded row starts
    int*    bsum   = (int*)alloc((size_t)4 * SCB * 4);
    float*  nsrc   = (float*)alloc((size_t)4 * NN * 4);
    float*  ndst   = (float*)alloc((size_t)4 * NN * 4);
    ushort* csr    = (ushort*)alloc((size_t)4 * PEN * 2);     // u16, 4-edge padded
    int*    dhp    = (int*)alloc((size_t)4 * DCH * 256 * 4);
    int*    dbase  = (int*)alloc((size_t)4 * 256 * 4);
    int*    perm   = (int*)alloc((size_t)4 * NN * 4);
    ushort* wt1    = (ushort*)alloc((size_t)320 * 136 * 2);
    ushort* wt2    = (ushort*)alloc((size_t)320 * 328 * 2);
    ushort* wt3    = (ushort*)alloc((size_t)320 * 328 * 2);
    uint*   partS  = (uint*)alloc((size_t)4 * NCH * PBS);     // 12.8 MB
    uint*   partD  = (uint*)alloc((size_t)4 * NCH * PBS);     // 12.8 MB

    // batched-4 tail buffers need hbuf4 (64 MB) + mbuf4 (128 MB).
    size_t need_tail = ((size_t)4 * 5 * (NN + 1) * 64 + 255 + (size_t)4 * NN * 320 * 2 + 255);
    size_t used = (size_t)(w - (char*)d_ws);
    bool batched = (ws_size >= used + need_tail + 4096);

    uint *hbuf, *mbuf, *xs, *m1;
    if (batched) {
        hbuf = (uint*)alloc((size_t)4 * 5 * (NN + 1) * 64); // [g][5][(NN+1)][64B]
        mbuf = (uint*)alloc((size_t)4 * NN * 320 * 2);      // [g][NN][320] bf16
        xs   = partS;   // [g][2][(NN+1)][64B] = 25.6 MB over partS+partD (contig)
        m1   = mbuf;    // [g][NN][128] bf16 = 51.2 MB; lifetime disjoint w/ mbuf
    } else {
        hbuf = (uint*)alloc((size_t)5 * (NN + 1) * 64);     // single graph
        mbuf = (uint*)alloc((size_t)NN * 320 * 2);
        xs   = partS;   // 6.4 MB
        m1   = partD;   // 12.8 MB
    }

    (void)hipMemsetAsync(accum, 0, 256, stream);

    wtrans_kernel<<<(320 * 136 + 255) / 256, 256, 0, stream>>>((const float*)d_in[12], wt1, 128, 136);
    wtrans_kernel<<<(320 * 328 + 255) / 256, 256, 0, stream>>>((const float*)d_in[14], wt2, 304, 328);
    wtrans_kernel<<<(320 * 328 + 255) / 256, 256, 0, stream>>>((const float*)d_in[16], wt3, 304, 328);

    GP S, D;
    FP X;
    for (int g = 0; g < 4; g++) {
        S.p[g] = (const int*)d_in[1 + 3 * g];
        D.p[g] = (const int*)d_in[2 + 3 * g];
        X.p[g] = (const float*)d_in[3 * g];
    }
    hist_kernel<<<dim3(NCH, 2, 4), 256, 0, stream>>>(S, D, partS, partD);
    reduce_kernel<<<(4 * NN + 255) / 256, 256, 0, stream>>>((const uchar*)partS, (uchar*)partD,
                                                            nsrc, ndst, degd);
    scan1_kernel<<<dim3(SCB, 4), 1024, 0, stream>>>(degd, rs, bsum);
    scan2_kernel<<<1, 256, 0, stream>>>(bsum, rs);
    scan3_kernel<<<dim3(SCB, 4), 1024, 0, stream>>>(bsum, rs);
    cfill_kernel<<<(4 * PEN / 2 + 255) / 256, 256, 0, stream>>>((uint*)csr);
    scatter_kernel<<<dim3(NCH, 4), 256, 0, stream>>>(S, D, rs, (const uchar*)partD, csr);
    dhist_kernel<<<dim3(DCH, 4), 256, 0, stream>>>(degd, dhp);
    dscan_kernel<<<1, 256, 0, stream>>>(dhp, dbase);
    dscatter_kernel<<<dim3(DCH, 4), 256, 0, stream>>>(degd, dhp, dbase, perm);
    padzero_kernel<<<1, 512, 0, stream>>>(xs, batched ? 8 : 2, hbuf, batched ? 20 : 5);

    const float* b1 = (const float*)d_in[13];
    const float* b2 = (const float*)d_in[15];
    const float* b3 = (const float*)d_in[17];

    if (batched) {
        dim3 pgrid((NN * 16 + 255) / 256, 4);
        dim3 sgrid1((NN + 63) / 64, 2, 4);
        dim3 sgrid2((NN + 63) / 64, 5, 4);
        dim3 ggrid(4, (NN + 127) / 128, 4);
        prescale_kernel<<<pgrid, 256, 0, stream>>>(X, nsrc, xs);
        spmm_kernel<<<sgrid1, 256, 0, stream>>>((const u4v*)xs, rs, csr,
                                                ndst, perm, (u4v*)m1, 16);
        gemm_kernel<4, false><<<ggrid, 256, 0, stream>>>((const ushort*)m1, 128, wt1, 136, b1, nsrc,
                                                         (uchar*)hbuf, nullptr, NN);
        spmm_kernel<<<sgrid2, 256, 0, stream>>>((const u4v*)hbuf, rs, csr,
                                                ndst, perm, (u4v*)mbuf, 40);
        gemm_kernel<10, false><<<ggrid, 256, 0, stream>>>((const ushort*)mbuf, 320, wt2, 328, b2, nsrc,
                                                          (uchar*)hbuf, nullptr, NN);
        spmm_kernel<<<sgrid2, 256, 0, stream>>>((const u4v*)hbuf, rs, csr,
                                                ndst, perm, (u4v*)mbuf, 40);
        gemm_kernel<10, true><<<ggrid, 256, 0, stream>>>((const ushort*)mbuf, 320, wt3, 328, b3, nullptr,
                                                         nullptr, accum, NN);
    } else {
        dim3 pgrid((NN * 16 + 255) / 256, 1);
        dim3 sgrid1((NN + 63) / 64, 2);
        dim3 sgrid2((NN + 63) / 64, 5);
        dim3 ggrid(4, (NN + 127) / 128);
        for (int g = 0; g < 4; g++) {
            FP Xg;
            Xg.p[0] = Xg.p[1] = Xg.p[2] = Xg.p[3] = (const float*)d_in[3 * g];
            const float* nsg = nsrc + g * NN;
            const float* ndg = ndst + g * NN;
            const int* rsg = rs + g * (NN + 1);
            const ushort* csrg = csr + (size_t)g * PEN;
            const int* permg = perm + g * NN;

            prescale_kernel<<<pgrid, 256, 0, stream>>>(Xg, nsg, xs);
            spmm_kernel<<<sgrid1, 256, 0, stream>>>((const u4v*)xs, rsg, csrg,
                                                    ndg, permg, (u4v*)m1, 16);
            gemm_kernel<4, false><<<ggrid, 256, 0, stream>>>((const ushort*)m1, 128, wt1, 136, b1, nsg,
                                                             (uchar*)hbuf, nullptr, NN);
            spmm_kernel<<<sgrid2, 256, 0, stream>>>((const u4v*)hbuf, rsg, csrg,
                                                    ndg, permg, (u4v*)mbuf, 40);
            gemm_kernel<10, false><<<ggrid, 256, 0, stream>>>((const ushort*)mbuf, 320, wt2, 328, b2, nsg,
                                                              (uchar*)hbuf, nullptr, NN);
            spmm_kernel<<<sgrid2, 256, 0, stream>>>((const u4v*)hbuf, rsg, csrg,
                                                    ndg, permg, (u4v*)mbuf, 40);
            gemm_kernel<10, true><<<ggrid, 256, 0, stream>>>((const ushort*)mbuf, 320, wt3, 328, b3, nullptr,
                                                             nullptr, accum, NN);
        }
    }
    finalize_kernel<<<1, 1, 0, stream>>>(accum, (float*)d_out);
}

// Round 10
// 1031.349 us; speedup vs baseline: 1.1163x; 1.1163x over previous
//
#include <hip/hip_runtime.h>
#include <hip/hip_bf16.h>

// GCN1: 3-layer GraphConv x 4 graphs -> scalar grand mean.
// R17: R12 base (best, 1054us) + panel-XCD colocation for GEMM. R14-R16
// proved per-wave MLP forcing fails (compiler re-serializes; VGPR stays
// ~44-56) and runs slower than R12's LDS-staged GEMM. Accounting says the
// GEMM binds on L2-fill: grid (4,391,G) puts a panel's 4 n-tile blocks on
// 4 XCDs (A filled 4x: 512MB L2-fill, FETCH 252MB). Fix: 1-D grid, decode
// id=grp*32+nt*8+r8, chunk=grp*8+r8 -> the 4 n-tile blocks share id%8 =
// one XCD = panel filled once; panels still spread over all 8 XCDs.
// Retains R12 8-deep-MLP spmm, R10 graph-batching, R9b layouts (64B packed
// rows, full-line gathers, packed f2 accumulate, nontemporal stores,
// padded CSR + degree-sorted perm, atomic-free CSR build, layer-3
// reduction into double).

#define NN 50000
#define EN 800000
#define PEN 950000        // padded edges per graph (EN + 3*NN upper bound)
#define NCH 64            // CSR chunks per graph
#define CHE 12500         // edges per chunk (NCH*CHE == EN)
#define PBS 50016         // padded per-chunk histogram bytes (>= NN, %4==0)
#define SCB 49            // scan blocks per graph (49*1024 >= NN)
#define DCH 13            // degree-sort chunks per graph
#define DCN 4096          // nodes per degree-sort chunk (13*4096 >= NN)
#define CPG 391           // gemm row-chunks per graph (391*128 >= NN)

typedef unsigned int uint;
typedef unsigned short ushort;
typedef unsigned char uchar;
typedef short s8v __attribute__((ext_vector_type(8)));
typedef float f4v __attribute__((ext_vector_type(4)));
typedef float f2v __attribute__((ext_vector_type(2)));
typedef uint u4v __attribute__((ext_vector_type(4)));

__device__ inline ushort f2bf(float f) {
    uint u = __float_as_uint(f);
    uint r = (u + 0x7FFFu + ((u >> 16) & 1u)) >> 16;
    return (ushort)r;
}
__device__ inline uint pk2(float lo, float hi) {
    return (uint)f2bf(lo) | ((uint)f2bf(hi) << 16);
}
__device__ inline f4v mfma16(s8v a, s8v b, f4v c) {
    return __builtin_amdgcn_mfma_f32_16x16x32_bf16(a, b, c, 0, 0, 0);
}
__device__ inline uchar f2fp8(float f) {
    return (uchar)(__builtin_amdgcn_cvt_pk_fp8_f32(f, 0.f, 0, false) & 0xFF);
}
// 16 fp8 bytes -> 8 packed float2 accumulators (v_pk_add_f32).
__device__ inline void acc16(u4v d, f2v* a) {
    a[0] += __builtin_amdgcn_cvt_pk_f32_fp8(d.x, false);
    a[1] += __builtin_amdgcn_cvt_pk_f32_fp8(d.x, true);
    a[2] += __builtin_amdgcn_cvt_pk_f32_fp8(d.y, false);
    a[3] += __builtin_amdgcn_cvt_pk_f32_fp8(d.y, true);
    a[4] += __builtin_amdgcn_cvt_pk_f32_fp8(d.z, false);
    a[5] += __builtin_amdgcn_cvt_pk_f32_fp8(d.z, true);
    a[6] += __builtin_amdgcn_cvt_pk_f32_fp8(d.w, false);
    a[7] += __builtin_amdgcn_cvt_pk_f32_fp8(d.w, true);
}

struct GP { const int* p[4]; };
struct FP { const float* p[4]; };

// ---- CSR build (atomic-free) ----------------------------------------------

__global__ __launch_bounds__(256) void hist_kernel(GP src, GP dst,
                                                   uint* __restrict__ partS,
                                                   uint* __restrict__ partD) {
    int b = blockIdx.x, dir = blockIdx.y, g = blockIdx.z;
    const int* idx = dir ? dst.p[g] : src.p[g];
    __shared__ uint lh[PBS / 4];
    for (int i = threadIdx.x; i < PBS / 4; i += 256) lh[i] = 0;
    __syncthreads();
    int e0 = b * CHE;
    for (int e = e0 + threadIdx.x; e < e0 + CHE; e += 256) {
        uint n = (uint)idx[e];
        atomicAdd(&lh[n >> 2], 1u << (8 * (n & 3)));   // LDS atomic only
    }
    __syncthreads();
    uint* out = (dir ? partD : partS) + (size_t)(g * NCH + b) * (PBS / 4);
    for (int i = threadIdx.x; i < PBS / 4; i += 256) out[i] = lh[i];
}

__global__ __launch_bounds__(256) void reduce_kernel(const uchar* __restrict__ partS,
                                                     uchar* __restrict__ partD,
                                                     float* __restrict__ ns,
                                                     float* __restrict__ nd,
                                                     int* __restrict__ degd) {
    int idx = blockIdx.x * 256 + threadIdx.x;
    if (idx >= 4 * NN) return;
    int g = idx / NN, n = idx - g * NN;
    const uchar* ps = partS + (size_t)(g * NCH) * PBS + n;
    uint ss = 0;
    for (int b = 0; b < NCH; b++) ss += ps[(size_t)b * PBS];
    uchar* pd = partD + (size_t)(g * NCH) * PBS + n;
    uint run = 0;
    for (int b = 0; b < NCH; b++) {
        uint v = pd[(size_t)b * PBS];
        pd[(size_t)b * PBS] = (uchar)run;
        run += v;
    }
    ns[idx] = rsqrtf((float)max(ss, 1u));
    nd[idx] = rsqrtf((float)max(run, 1u));
    degd[idx] = (int)run;
}

// scan over PADDED degree (deg+3)&~3 -> prs row starts (4-edge aligned).
__global__ __launch_bounds__(1024) void scan1_kernel(const int* __restrict__ degd,
                                                     int* __restrict__ rs_all,
                                                     int* __restrict__ bsum) {
    int j = blockIdx.x, g = blockIdx.y;
    int i = j * 1024 + threadIdx.x;
    int v = (i < NN) ? ((degd[g * NN + i] + 3) & ~3) : 0;
    int lane = threadIdx.x & 63, w = threadIdx.x >> 6;
    int x = v;
    #pragma unroll
    for (int off = 1; off < 64; off <<= 1) {
        int t = __shfl_up(x, off, 64);
        if (lane >= off) x += t;
    }
    __shared__ int ws[17];
    if (lane == 63) ws[w] = x;
    __syncthreads();
    if (threadIdx.x == 0) {
        int run = 0;
        #pragma unroll
        for (int k = 0; k < 16; k++) { int t = ws[k]; ws[k] = run; run += t; }
        ws[16] = run;
    }
    __syncthreads();
    if (i < NN) rs_all[g * (NN + 1) + i] = ws[w] + x - v;
    if (threadIdx.x == 0) bsum[g * SCB + j] = ws[16];
}

__global__ void scan2_kernel(int* __restrict__ bsum, int* __restrict__ rs_all) {
    int g = threadIdx.x >> 6, lane = threadIdx.x & 63;
    int v = (lane < SCB) ? bsum[g * SCB + lane] : 0;
    int x = v;
    #pragma unroll
    for (int off = 1; off < 64; off <<= 1) {
        int t = __shfl_up(x, off, 64);
        if (lane >= off) x += t;
    }
    if (lane < SCB) bsum[g * SCB + lane] = x - v;   // exclusive
    if (lane == 63) rs_all[g * (NN + 1) + NN] = x;  // total padded edges
}

__global__ __launch_bounds__(1024) void scan3_kernel(const int* __restrict__ bsum,
                                                     int* __restrict__ rs_all) {
    int j = blockIdx.x, g = blockIdx.y;
    int i = j * 1024 + threadIdx.x;
    int off = bsum[g * SCB + j];
    if (i < NN) rs_all[g * (NN + 1) + i] += off;
}

// fill padded csr with the zero-row id NN (pad slots survive scatter).
__global__ __launch_bounds__(256) void cfill_kernel(uint* __restrict__ csr2) {
    int i = blockIdx.x * 256 + threadIdx.x;
    if (i < 4 * PEN / 2) csr2[i] = (uint)NN | ((uint)NN << 16);
}

__global__ __launch_bounds__(256) void scatter_kernel(GP src, GP dst,
                                                      const int* __restrict__ rs_all,
                                                      const uchar* __restrict__ pf,
                                                      ushort* __restrict__ csr) {
    int b = blockIdx.x, g = blockIdx.y;
    __shared__ uint lc[PBS / 4];
    for (int i = threadIdx.x; i < PBS / 4; i += 256) lc[i] = 0;
    __syncthreads();
    const int* sp = src.p[g];
    const int* dp = dst.p[g];
    const int* rs = rs_all + g * (NN + 1);
    const uchar* pfb = pf + (size_t)(g * NCH + b) * PBS;
    ushort* csrg = csr + (size_t)g * PEN;
    int e0 = b * CHE;
    for (int e = e0 + threadIdx.x; e < e0 + CHE; e += 256) {
        uint d = (uint)dp[e];
        int s = sp[e];
        uint sh = 8 * (d & 3);
        uint old = atomicAdd(&lc[d >> 2], 1u << sh);
        uint r = (old >> sh) & 0xFFu;
        csrg[rs[d] + (int)pfb[d] + (int)r] = (ushort)s;
    }
}

// ---- degree counting sort (chunked, atomic-free) -> perm -------------------

__global__ __launch_bounds__(256) void dhist_kernel(const int* __restrict__ degd,
                                                    int* __restrict__ dhp) {
    int b = blockIdx.x, g = blockIdx.y;
    __shared__ int lh[256];
    lh[threadIdx.x] = 0;
    __syncthreads();
    int n0 = b * DCN, nend = min(n0 + DCN, NN);
    for (int i = n0 + threadIdx.x; i < nend; i += 256) {
        int d = degd[g * NN + i];
        atomicAdd(&lh[d < 255 ? d : 255], 1);   // LDS only
    }
    __syncthreads();
    dhp[(g * DCH + b) * 256 + threadIdx.x] = lh[threadIdx.x];
}

__global__ void dscan_kernel(int* __restrict__ dhp, int* __restrict__ dbase) {
    int tid = threadIdx.x, lane = tid & 63, w = tid >> 6;
    __shared__ int ws[4];
    for (int g = 0; g < 4; g++) {
        int run = 0;
        for (int c = 0; c < DCH; c++) {
            int v = dhp[(g * DCH + c) * 256 + tid];
            dhp[(g * DCH + c) * 256 + tid] = run;
            run += v;
        }
        int x = run;
        #pragma unroll
        for (int off = 1; off < 64; off <<= 1) {
            int t = __shfl_up(x, off, 64);
            if (lane >= off) x += t;
        }
        if (lane == 63) ws[w] = x;
        __syncthreads();
        int prefix = 0;
        for (int j = 0; j < w; j++) prefix += ws[j];
        dbase[g * 256 + tid] = prefix + x - run;
        __syncthreads();
    }
}

__global__ __launch_bounds__(256) void dscatter_kernel(const int* __restrict__ degd,
                                                       const int* __restrict__ dhp,
                                                       const int* __restrict__ dbase,
                                                       int* __restrict__ perm) {
    int b = blockIdx.x, g = blockIdx.y;
    __shared__ int lc[256];
    lc[threadIdx.x] = 0;
    __syncthreads();
    int n0 = b * DCN, nend = min(n0 + DCN, NN);
    for (int i = n0 + threadIdx.x; i < nend; i += 256) {
        int d = degd[g * NN + i];
        d = d < 255 ? d : 255;
        int r = atomicAdd(&lc[d], 1);   // LDS only: within-chunk rank
        int pos = dbase[g * 256 + d] + dhp[(g * DCH + b) * 256 + d] + r;
        perm[g * NN + pos] = i;
    }
}

// ---- zero pad rows (row NN): nxs/nhb consecutive slice blocks --------------

__global__ void padzero_kernel(uint* __restrict__ xs, int nxs,
                               uint* __restrict__ hb, int nhb) {
    int t = threadIdx.x;
    if (t < nxs * 16) xs[(size_t)(t >> 4) * (NN + 1) * 16 + (size_t)NN * 16 + (t & 15)] = 0;
    if (t < nhb * 16) hb[(size_t)(t >> 4) * (NN + 1) * 16 + (size_t)NN * 16 + (t & 15)] = 0;
}

// ---- weight transpose/pad to bf16: Wt[n][k], stride WS = K+8 ---------------

__global__ __launch_bounds__(256) void wtrans_kernel(const float* __restrict__ W,
                                                     ushort* __restrict__ Wt,
                                                     int Kreal, int WS) {
    int idx = blockIdx.x * 256 + threadIdx.x;
    if (idx >= 320 * WS) return;
    int n = idx / WS, k = idx - n * WS;
    float v = (n < 304 && k < Kreal) ? W[k * 304 + n] : 0.f;
    Wt[idx] = f2bf(v);
}

// ---- prescale: xs = fp8(x * ns), [g][2][(NN+1)][64B]; blockIdx.y = graph ---

__global__ __launch_bounds__(256) void prescale_kernel(FP xp,
                                                       const float* __restrict__ ns,
                                                       uint* __restrict__ xs) {
    int g = blockIdx.y;
    const float* x = xp.p[g];
    ns += (size_t)g * NN;
    xs += (size_t)g * 2 * (NN + 1) * 16;
    int idx = blockIdx.x * 256 + threadIdx.x;   // over NN*16 units of 8 floats
    if (idx >= NN * 16) return;
    int row = idx >> 4, j = idx & 15;
    int sl = j >> 3, pos = j & 7;
    float nv = ns[row];
    float4 v0 = ((const float4*)x)[idx * 2];
    float4 v1 = ((const float4*)x)[idx * 2 + 1];
    int p0 = 0, p1 = 0;
    p0 = __builtin_amdgcn_cvt_pk_fp8_f32(v0.x * nv, v0.y * nv, p0, false);
    p0 = __builtin_amdgcn_cvt_pk_fp8_f32(v0.z * nv, v0.w * nv, p0, true);
    p1 = __builtin_amdgcn_cvt_pk_fp8_f32(v1.x * nv, v1.y * nv, p1, false);
    p1 = __builtin_amdgcn_cvt_pk_fp8_f32(v1.z * nv, v1.w * nv, p1, true);
    ((uint2*)xs)[(size_t)sl * (NN + 1) * 8 + row * 8 + pos] = make_uint2((uint)p0, (uint)p1);
}

// ---- SpMM (64B packed rows, 1-line dwordx4 group gathers, 8-deep MLP) ------
// xsl: S slices x [(NN+1)][64B]. Wave = 16 groups x 4 lanes x 16B = 1 line
// per gather. Grid (ceil(NN/64), SL, G). Inner loop: 8 edges/iter, 8 lines
// in flight, two accumulator banks (halved add chains). Rows are 4-edge
// padded; the odd quad is peeled first so the main loop is 8-aligned.
__global__ __launch_bounds__(256) void spmm_kernel(const u4v* __restrict__ xsl,
                                                   const int* __restrict__ prs,
                                                   const ushort* __restrict__ csr,
                                                   const float* __restrict__ nd,
                                                   const int* __restrict__ perm,
                                                   u4v* __restrict__ out,
                                                   int ostride) {
    int g = blockIdx.z, SL = gridDim.y;
    xsl += (size_t)g * SL * (NN + 1) * 4;
    prs += (size_t)g * (NN + 1);
    csr += (size_t)g * PEN;
    nd  += (size_t)g * NN;
    perm += (size_t)g * NN;
    out += (size_t)g * NN * ostride;

    int wv = threadIdx.x >> 6, lane = threadIdx.x & 63;
    int grp = lane >> 2, gl = lane & 3;
    int slot = blockIdx.x * 64 + wv * 16 + grp;
    int sl = blockIdx.y;
    const u4v* base = xsl + (size_t)sl * (NN + 1) * 4 + gl;
    bool ok = slot < NN;
    int node = ok ? perm[slot] : 0;
    int p0 = ok ? prs[node] : 0, p1 = ok ? prs[node + 1] : 0;
    f2v a[8], b[8];
    #pragma unroll
    for (int i = 0; i < 8; i++) { a[i] = (f2v){0.f, 0.f}; b[i] = (f2v){0.f, 0.f}; }
    int e = p0;
    if ((p1 - p0) & 4) {
        uint2 e4 = *(const uint2*)(csr + e);
        uint s0 = e4.x & 0xFFFFu, s1 = e4.x >> 16;
        uint s2 = e4.y & 0xFFFFu, s3 = e4.y >> 16;
        u4v d0 = base[s0 * 4];
        u4v d1 = base[s1 * 4];
        u4v d2 = base[s2 * 4];
        u4v d3 = base[s3 * 4];
        acc16(d0, a); acc16(d1, b); acc16(d2, a); acc16(d3, b);
        e += 4;
    }
    for (; e < p1; e += 8) {
        uint2 q0 = *(const uint2*)(csr + e);
        uint2 q1 = *(const uint2*)(csr + e + 4);
        uint s0 = q0.x & 0xFFFFu, s1 = q0.x >> 16;
        uint s2 = q0.y & 0xFFFFu, s3 = q0.y >> 16;
        uint s4 = q1.x & 0xFFFFu, s5 = q1.x >> 16;
        uint s6 = q1.y & 0xFFFFu, s7 = q1.y >> 16;
        u4v d0 = base[s0 * 4];
        u4v d1 = base[s1 * 4];
        u4v d2 = base[s2 * 4];
        u4v d3 = base[s3 * 4];
        u4v d4 = base[s4 * 4];
        u4v d5 = base[s5 * 4];
        u4v d6 = base[s6 * 4];
        u4v d7 = base[s7 * 4];
        acc16(d0, a); acc16(d1, b); acc16(d2, a); acc16(d3, b);
        acc16(d4, a); acc16(d5, b); acc16(d6, a); acc16(d7, b);
    }
    if (ok) {
        float nv = nd[node];
        f2v nv2 = {nv, nv};
        f2v c0 = (a[0] + b[0]) * nv2, c1 = (a[1] + b[1]) * nv2;
        f2v c2 = (a[2] + b[2]) * nv2, c3 = (a[3] + b[3]) * nv2;
        f2v c4 = (a[4] + b[4]) * nv2, c5 = (a[5] + b[5]) * nv2;
        f2v c6 = (a[6] + b[6]) * nv2, c7 = (a[7] + b[7]) * nv2;
        u4v o0, o1;
        o0.x = pk2(c0[0], c0[1]); o0.y = pk2(c1[0], c1[1]);
        o0.z = pk2(c2[0], c2[1]); o0.w = pk2(c3[0], c3[1]);
        o1.x = pk2(c4[0], c4[1]); o1.y = pk2(c5[0], c5[1]);
        o1.z = pk2(c6[0], c6[1]); o1.w = pk2(c7[0], c7[1]);
        u4v* op = out + (size_t)node * ostride + sl * 8 + gl * 2;
        __builtin_nontemporal_store(o0, op);
        __builtin_nontemporal_store(o1, op + 1);
    }
}

// ---- GEMM: C[M x 320] = A[M x K] @ Wt^T, epilogue relu(+bias) --------------
// R12 staged structure, 1-D grid with panel-XCD colocation: id = grp*32 +
// nt*8 + r8, chunk = grp*8 + r8 -> a panel's 4 n-tile blocks share id%8 =
// one XCD -> A-panel filled into one L2 (was 4). !REDUCE writes fp8 into
// 5-slice 64B-packed layout; REDUCE sums into double.

template<int KSTEPS, bool REDUCE>
__global__ __launch_bounds__(256) void gemm_kernel(const ushort* __restrict__ A, int astride,
                                                   const ushort* __restrict__ Wt,
                                                   const float* __restrict__ bias,
                                                   const float* __restrict__ ns,
                                                   uchar* __restrict__ Hout,
                                                   double* __restrict__ accum,
                                                   int CH) {
    constexpr int K = KSTEPS * 32;
    constexpr int WS = K + 8;   // pad: 2-way LDS conflicts only (free)
    int b = blockIdx.x;
    int r8 = b & 7;
    int nt4 = (b >> 3) & 3;
    int grp = b >> 5;
    int chunk = grp * 8 + r8;
    if (chunk >= CH) return;
    int g = chunk / CPG, rc = chunk - g * CPG;
    int M = NN;

    __shared__ __align__(16) ushort wt[80 * WS];
    __shared__ float redbuf[4];
    A += (size_t)g * NN * astride;
    int tid = threadIdx.x, lane = tid & 63, wv = tid >> 6;
    int nb = nt4 * 80;
    int r0 = rc * 128 + wv * 32;

    {   // stage 80 rows of Wt (16B vectors)
        const s8v* src = (const s8v*)(Wt + (size_t)nb * WS);
        s8v* dst = (s8v*)wt;
        for (int i = tid; i < 80 * WS / 8; i += 256) dst[i] = src[i];
    }
    __syncthreads();

    f4v acc[2][5];
    #pragma unroll
    for (int t = 0; t < 2; t++)
        #pragma unroll
        for (int j = 0; j < 5; j++) acc[t][j] = (f4v){0.f, 0.f, 0.f, 0.f};

    int m15 = lane & 15;
    int kq = (lane >> 4) * 8;
    int ar0 = min(r0 + m15, M - 1);
    int ar1 = min(r0 + 16 + m15, M - 1);
    const ushort* a0p = A + (size_t)ar0 * astride + kq;
    const ushort* a1p = A + (size_t)ar1 * astride + kq;
    const ushort* bb = wt + (size_t)m15 * WS + kq;

    #pragma unroll
    for (int ks = 0; ks < KSTEPS; ks++) {
        s8v af0 = *(const s8v*)(a0p + ks * 32);
        s8v af1 = *(const s8v*)(a1p + ks * 32);
        #pragma unroll
        for (int nt = 0; nt < 5; nt++) {
            s8v bf = *(const s8v*)(bb + nt * 16 * WS + ks * 32);
            acc[0][nt] = mfma16(af0, bf, acc[0][nt]);
            acc[1][nt] = mfma16(af1, bf, acc[1][nt]);
        }
    }

    int rq = (lane >> 4) * 4;   // C/D: col = lane&15, row = (lane>>4)*4 + reg
    if constexpr (!REDUCE) {
        const float* nsg = ns + (size_t)g * NN;
        uchar* hg = Hout + (size_t)g * 5 * (NN + 1) * 64;
        float nsv[2][4];
        #pragma unroll
        for (int t = 0; t < 2; t++)
            #pragma unroll
            for (int r = 0; r < 4; r++) {
                int row = r0 + t * 16 + rq + r;
                nsv[t][r] = (row < M) ? nsg[row] : 0.f;
            }
        #pragma unroll
        for (int nt = 0; nt < 5; nt++) {
            int col = nb + nt * 16 + m15;
            float bv = (col < 304) ? bias[col] : 0.f;
            int sl = col >> 6, cw = col & 63;
            uchar* hp = hg + (size_t)sl * (NN + 1) * 64 + cw;
            #pragma unroll
            for (int t = 0; t < 2; t++)
                #pragma unroll
                for (int r = 0; r < 4; r++) {
                    int row = r0 + t * 16 + rq + r;
                    if (row < M) {
                        float y = fmaxf(acc[t][nt][r] + bv, 0.f) * nsv[t][r];
                        hp[(size_t)row * 64] = f2fp8(y);
                    }
                }
        }
    } else {
        float s = 0.f;
        #pragma unroll
        for (int nt = 0; nt < 5; nt++) {
            int col = nb + nt * 16 + m15;
            float bv = (col < 304) ? bias[col] : 0.f;
            #pragma unroll
            for (int t = 0; t < 2; t++)
                #pragma unroll
                for (int r = 0; r < 4; r++) {
                    int row = r0 + t * 16 + rq + r;
                    if (row < M && col < 304) s += fmaxf(acc[t][nt][r] + bv, 0.f);
                }
        }
        #pragma unroll
        for (int off = 32; off; off >>= 1) s += __shfl_xor(s, off, 64);
        if (lane == 0) redbuf[wv] = s;
        __syncthreads();
        if (tid == 0) {
            double bsum = (double)redbuf[0] + redbuf[1] + redbuf[2] + redbuf[3];
            atomicAdd(accum, bsum);
        }
    }
}

__global__ void finalize_kernel(const double* __restrict__ accum, float* __restrict__ out) {
    out[0] = (float)(accum[0] / (double)(4.0 * NN * 304.0));
}

// ---- host ------------------------------------------------------------------

extern "C" void kernel_launch(void* const* d_in, const int* in_sizes, int n_in,
                              void* d_out, int out_size, void* d_ws, size_t ws_size,
                              hipStream_t stream) {
    char* w = (char*)d_ws;
    auto alloc = [&](size_t bytes) {
        char* p = w;
        w += (bytes + 255) & ~(size_t)255;
        return p;
    };
    double* accum  = (double*)alloc(256);
    int*    degd   = (int*)alloc((size_t)4 * NN * 4);
    int*    rs     = (int*)alloc((size_t)4 * (NN + 1) * 4);   // padded row starts
    int*    bsum   = (int*)alloc((size_t)4 * SCB * 4);
    float*  nsrc   = (float*)alloc((size_t)4 * NN * 4);
    float*  ndst   = (float*)alloc((size_t)4 * NN * 4);
    ushort* csr    = (ushort*)alloc((size_t)4 * PEN * 2);     // u16, 4-edge padded
    int*    dhp    = (int*)alloc((size_t)4 * DCH * 256 * 4);
    int*    dbase  = (int*)alloc((size_t)4 * 256 * 4);
    int*    perm   = (int*)alloc((size_t)4 * NN * 4);
    ushort* wt1    = (ushort*)alloc((size_t)320 * 136 * 2);
    ushort* wt2    = (ushort*)alloc((size_t)320 * 328 * 2);
    ushort* wt3    = (ushort*)alloc((size_t)320 * 328 * 2);
    uint*   partS  = (uint*)alloc((size_t)4 * NCH * PBS);     // 12.8 MB
    uint*   partD  = (uint*)alloc((size_t)4 * NCH * PBS);     // 12.8 MB

    // batched-4 tail buffers need hbuf4 (64 MB) + mbuf4 (128 MB).
    size_t need_tail = ((size_t)4 * 5 * (NN + 1) * 64 + 255 + (size_t)4 * NN * 320 * 2 + 255);
    size_t used = (size_t)(w - (char*)d_ws);
    bool batched = (ws_size >= used + need_tail + 4096);

    uint *hbuf, *mbuf, *xs, *m1;
    if (batched) {
        hbuf = (uint*)alloc((size_t)4 * 5 * (NN + 1) * 64); // [g][5][(NN+1)][64B]
        mbuf = (uint*)alloc((size_t)4 * NN * 320 * 2);      // [g][NN][320] bf16
        xs   = partS;   // [g][2][(NN+1)][64B] = 25.6 MB over partS+partD (contig)
        m1   = mbuf;    // [g][NN][128] bf16 = 51.2 MB; lifetime disjoint w/ mbuf
    } else {
        hbuf = (uint*)alloc((size_t)5 * (NN + 1) * 64);     // single graph
        mbuf = (uint*)alloc((size_t)NN * 320 * 2);
        xs   = partS;   // 6.4 MB
        m1   = partD;   // 12.8 MB
    }

    (void)hipMemsetAsync(accum, 0, 256, stream);

    wtrans_kernel<<<(320 * 136 + 255) / 256, 256, 0, stream>>>((const float*)d_in[12], wt1, 128, 136);
    wtrans_kernel<<<(320 * 328 + 255) / 256, 256, 0, stream>>>((const float*)d_in[14], wt2, 304, 328);
    wtrans_kernel<<<(320 * 328 + 255) / 256, 256, 0, stream>>>((const float*)d_in[16], wt3, 304, 328);

    GP S, D;
    FP X;
    for (int g = 0; g < 4; g++) {
        S.p[g] = (const int*)d_in[1 + 3 * g];
        D.p[g] = (const int*)d_in[2 + 3 * g];
        X.p[g] = (const float*)d_in[3 * g];
    }
    hist_kernel<<<dim3(NCH, 2, 4), 256, 0, stream>>>(S, D, partS, partD);
    reduce_kernel<<<(4 * NN + 255) / 256, 256, 0, stream>>>((const uchar*)partS, (uchar*)partD,
                                                            nsrc, ndst, degd);
    scan1_kernel<<<dim3(SCB, 4), 1024, 0, stream>>>(degd, rs, bsum);
    scan2_kernel<<<1, 256, 0, stream>>>(bsum, rs);
    scan3_kernel<<<dim3(SCB, 4), 1024, 0, stream>>>(bsum, rs);
    cfill_kernel<<<(4 * PEN / 2 + 255) / 256, 256, 0, stream>>>((uint*)csr);
    scatter_kernel<<<dim3(NCH, 4), 256, 0, stream>>>(S, D, rs, (const uchar*)partD, csr);
    dhist_kernel<<<dim3(DCH, 4), 256, 0, stream>>>(degd, dhp);
    dscan_kernel<<<1, 256, 0, stream>>>(dhp, dbase);
    dscatter_kernel<<<dim3(DCH, 4), 256, 0, stream>>>(degd, dhp, dbase, perm);
    padzero_kernel<<<1, 512, 0, stream>>>(xs, batched ? 8 : 2, hbuf, batched ? 20 : 5);

    const float* b1 = (const float*)d_in[13];
    const float* b2 = (const float*)d_in[15];
    const float* b3 = (const float*)d_in[17];

    if (batched) {
        dim3 pgrid((NN * 16 + 255) / 256, 4);
        dim3 sgrid1((NN + 63) / 64, 2, 4);
        dim3 sgrid2((NN + 63) / 64, 5, 4);
        int CH = 4 * CPG;                    // 1564 chunks
        int BG = ((CH + 7) / 8) * 32;        // 6272 blocks (16 no-op)
        prescale_kernel<<<pgrid, 256, 0, stream>>>(X, nsrc, xs);
        spmm_kernel<<<sgrid1, 256, 0, stream>>>((const u4v*)xs, rs, csr,
                                                ndst, perm, (u4v*)m1, 16);
        gemm_kernel<4, false><<<BG, 256, 0, stream>>>((const ushort*)m1, 128, wt1, b1, nsrc,
                                                      (uchar*)hbuf, nullptr, CH);
        spmm_kernel<<<sgrid2, 256, 0, stream>>>((const u4v*)hbuf, rs, csr,
                                                ndst, perm, (u4v*)mbuf, 40);
        gemm_kernel<10, false><<<BG, 256, 0, stream>>>((const ushort*)mbuf, 320, wt2, b2, nsrc,
                                                       (uchar*)hbuf, nullptr, CH);
        spmm_kernel<<<sgrid2, 256, 0, stream>>>((const u4v*)hbuf, rs, csr,
                                                ndst, perm, (u4v*)mbuf, 40);
        gemm_kernel<10, true><<<BG, 256, 0, stream>>>((const ushort*)mbuf, 320, wt3, b3, nullptr,
                                                      nullptr, accum, CH);
    } else {
        dim3 pgrid((NN * 16 + 255) / 256, 1);
        dim3 sgrid1((NN + 63) / 64, 2);
        dim3 sgrid2((NN + 63) / 64, 5);
        int CH = CPG;                        // 391 chunks -> decode g = 0
        int BG = ((CH + 7) / 8) * 32;        // 1568 blocks
        for (int g = 0; g < 4; g++) {
            FP Xg;
            Xg.p[0] = Xg.p[1] = Xg.p[2] = Xg.p[3] = (const float*)d_in[3 * g];
            const float* nsg = nsrc + g * NN;
            const float* ndg = ndst + g * NN;
            const int* rsg = rs + g * (NN + 1);
            const ushort* csrg = csr + (size_t)g * PEN;
            const int* permg = perm + g * NN;

            prescale_kernel<<<pgrid, 256, 0, stream>>>(Xg, nsg, xs);
            spmm_kernel<<<sgrid1, 256, 0, stream>>>((const u4v*)xs, rsg, csrg,
                                                    ndg, permg, (u4v*)m1, 16);
            gemm_kernel<4, false><<<BG, 256, 0, stream>>>((const ushort*)m1, 128, wt1, b1, nsg,
                                                          (uchar*)hbuf, nullptr, CH);
            spmm_kernel<<<sgrid2, 256, 0, stream>>>((const u4v*)hbuf, rsg, csrg,
                                                    ndg, permg, (u4v*)mbuf, 40);
            gemm_kernel<10, false><<<BG, 256, 0, stream>>>((const ushort*)mbuf, 320, wt2, b2, nsg,
                                                           (uchar*)hbuf, nullptr, CH);
            spmm_kernel<<<sgrid2, 256, 0, stream>>>((const u4v*)hbuf, rsg, csrg,
                                                    ndg, permg, (u4v*)mbuf, 40);
            gemm_kernel<10, true><<<BG, 256, 0, stream>>>((const ushort*)mbuf, 320, wt3, b3, nullptr,
                                                          nullptr, accum, CH);
        }
    }
    finalize_kernel<<<1, 1, 0, stream>>>(accum, (float*)d_out);
}